// Round 3
// baseline (466.628 us; speedup 1.0000x reference)
//
#include <hip/hip_runtime.h>

typedef __attribute__((ext_vector_type(8))) short short8;
typedef __attribute__((ext_vector_type(16))) float f32x16;

union Frag {
    short8 v;
    unsigned u[4];
};

__device__ __forceinline__ unsigned pack_bf16(float lo, float hi) {
    unsigned r;
    asm volatile("v_cvt_pk_bf16_f32 %0, %1, %2" : "=v"(r) : "v"(lo), "v"(hi));
    return r;
}

// ---------------- sort-by-dst machinery ----------------

__global__ __launch_bounds__(256)
void hist_kernel(const int* __restrict__ dst, int* __restrict__ hist, int E) {
    int i = blockIdx.x * blockDim.x + threadIdx.x;
    const int n = gridDim.x * blockDim.x;
    for (; i < E; i += n) atomicAdd(&hist[dst[i]], 1);
}

// single-block in-place exclusive scan (n up to a few hundred K)
__global__ __launch_bounds__(1024)
void scan_kernel(int* __restrict__ data, int n) {
    __shared__ int wave_sums[16];
    __shared__ int carry_s;
    const int tid = threadIdx.x;
    const int lane = tid & 63;
    const int wv = tid >> 6;
    if (tid == 0) carry_s = 0;
    __syncthreads();
    const int TILE = 4096;  // 1024 threads x 4
    for (int base = 0; base < n; base += TILE) {
        const int idx = base + tid * 4;
        int4 v = {0, 0, 0, 0};
        if (idx + 3 < n) {
            v = *reinterpret_cast<const int4*>(data + idx);
        } else {
            if (idx + 0 < n) v.x = data[idx + 0];
            if (idx + 1 < n) v.y = data[idx + 1];
            if (idx + 2 < n) v.z = data[idx + 2];
        }
        const int s0 = v.x, s1 = s0 + v.y, s2 = s1 + v.z, s3 = s2 + v.w;
        // wave inclusive scan of s3
        int ws = s3;
#pragma unroll
        for (int off = 1; off < 64; off <<= 1) {
            const int t = __shfl_up(ws, off, 64);
            if (lane >= off) ws += t;
        }
        if (lane == 63) wave_sums[wv] = ws;
        __syncthreads();
        const int carry = carry_s;
        int wbase = 0;
        for (int w = 0; w < wv; ++w) wbase += wave_sums[w];
        const int tb = carry + wbase + (ws - s3);  // exclusive base for this thread
        if (idx + 3 < n) {
            int4 o;
            o.x = tb; o.y = tb + s0; o.z = tb + s1; o.w = tb + s2;
            *reinterpret_cast<int4*>(data + idx) = o;
        } else {
            if (idx + 0 < n) data[idx + 0] = tb;
            if (idx + 1 < n) data[idx + 1] = tb + s0;
            if (idx + 2 < n) data[idx + 2] = tb + s1;
        }
        __syncthreads();
        if (tid == 0) {
            int tot = 0;
            for (int w = 0; w < 16; ++w) tot += wave_sums[w];
            carry_s = carry + tot;
        }
        __syncthreads();
    }
}

__global__ __launch_bounds__(256)
void scatter_kernel(const int* __restrict__ dst, int* __restrict__ cursor,
                    int* __restrict__ perm, int E) {
    int i = blockIdx.x * blockDim.x + threadIdx.x;
    const int n = gridDim.x * blockDim.x;
    for (; i < E; i += n) {
        const int p = atomicAdd(&cursor[dst[i]], 1);
        perm[p] = i;
    }
}

// ---------------- main edge kernel ----------------

__global__ __launch_bounds__(256, 2)
void gcmc_edge_mfma(const float* __restrict__ weight,
                    const float* __restrict__ prob_w,
                    const float* __restrict__ rscore_w,
                    const float* __restrict__ review_w,
                    const float* __restrict__ feat,
                    const float* __restrict__ cj,
                    const float* __restrict__ ci,
                    const int* __restrict__ src_idx,
                    const int* __restrict__ dst_idx,
                    const int* __restrict__ perm,   // nullable
                    float* __restrict__ out,
                    int E)
{
    const int lane = threadIdx.x & 63;
    const int h = lane >> 5;        // k-half
    const int c = lane & 31;        // row (A) / col (B, C/D)
    const int wid = blockIdx.x * (blockDim.x >> 6) + (threadIdx.x >> 6);
    const int nw = gridDim.x * (blockDim.x >> 6);

    const float4* rw4 = reinterpret_cast<const float4*>(review_w);
    const float4* pw4 = reinterpret_cast<const float4*>(prob_w);
    const float4* sw4 = reinterpret_cast<const float4*>(rscore_w);
    const float4* ft4 = reinterpret_cast<const float4*>(feat);

    // B fragments: B[k][o] = review_w[o][k]; lane holds col o = 32t+c,
    // k = 16s + 8h + j (j=0..7).
    Frag bf[2][4];
#pragma unroll
    for (int t = 0; t < 2; ++t) {
#pragma unroll
        for (int s = 0; s < 4; ++s) {
            const float4 r0 = rw4[(32 * t + c) * 16 + 4 * s + 2 * h];
            const float4 r1 = rw4[(32 * t + c) * 16 + 4 * s + 2 * h + 1];
            bf[t][s].u[0] = pack_bf16(r0.x, r0.y);
            bf[t][s].u[1] = pack_bf16(r0.z, r0.w);
            bf[t][s].u[2] = pack_bf16(r1.x, r1.y);
            bf[t][s].u[3] = pack_bf16(r1.z, r1.w);
        }
    }

    const int nbatch = E >> 5;

    for (int b = wid; b < nbatch; b += nw) {
        const int e0 = b << 5;
        const int pe = perm ? perm[e0 + c] : (e0 + c);   // this wave-half's edge id

        // ---- A fragments (feat rows, gathered) + f32 gate partial dots ----
        Frag af[4];
        float px = 0.0f, sx = 0.0f;
#pragma unroll
        for (int s = 0; s < 4; ++s) {
            const size_t base = (size_t)pe * 16 + 4 * s + 2 * h;
            const float4 f0 = ft4[base];
            const float4 f1 = ft4[base + 1];
            const float4 p0 = pw4[4 * s + 2 * h];
            const float4 p1 = pw4[4 * s + 2 * h + 1];
            const float4 q0 = sw4[4 * s + 2 * h];
            const float4 q1 = sw4[4 * s + 2 * h + 1];
            px += f0.x * p0.x + f0.y * p0.y + f0.z * p0.z + f0.w * p0.w
                + f1.x * p1.x + f1.y * p1.y + f1.z * p1.z + f1.w * p1.w;
            sx += f0.x * q0.x + f0.y * q0.y + f0.z * q0.z + f0.w * q0.w
                + f1.x * q1.x + f1.y * q1.y + f1.z * q1.z + f1.w * q1.w;
            af[s].u[0] = pack_bf16(f0.x, f0.y);
            af[s].u[1] = pack_bf16(f0.z, f0.w);
            af[s].u[2] = pack_bf16(f1.x, f1.y);
            af[s].u[3] = pack_bf16(f1.z, f1.w);
        }

        px += __shfl_xor(px, 32, 64);
        sx += __shfl_xor(sx, 32, 64);
        const float pa = __fdividef(1.0f, 1.0f + __expf(-px));
        const float gs = __fdividef(1.0f, 1.0f + __expf(-sx));

        const int se = src_idx[pe];
        const int de = dst_idx[pe];
        const float cjci = cj[se] * ci[de];
        const float Ae = pa * cjci;
        const float Be = gs * cjci;

        // ---- MFMA: rf_raw[32 edges][64 outs] ----
        f32x16 acc0 = {0.0f};
        f32x16 acc1 = {0.0f};
#pragma unroll
        for (int s = 0; s < 4; ++s) {
            acc0 = __builtin_amdgcn_mfma_f32_32x32x16_bf16(af[s].v, bf[0][s].v, acc0, 0, 0, 0);
            acc1 = __builtin_amdgcn_mfma_f32_32x32x16_bf16(af[s].v, bf[1][s].v, acc1, 0, 0, 0);
        }

        // ---- epilogue with run-length accumulation over equal dst ----
        // D layout: col=c, row e = (r&3)+8*(r>>2)+4h; e is monotone in r per half,
        // so dst-sorted edges form contiguous runs in r-order.
        int prev_d = -1;
        float r0acc = 0.0f, r1acc = 0.0f;
#pragma unroll
        for (int r = 0; r < 16; ++r) {
            const int e_lr = (r & 3) + 8 * (r >> 2) + 4 * h;
            const float Ar = __shfl(Ae, e_lr, 64);
            const float Br = __shfl(Be, e_lr, 64);
            const int sr = __shfl(se, e_lr, 64);
            const int dr = __shfl(de, e_lr, 64);
            const float w0 = weight[sr * 64 + c];
            const float w1 = weight[sr * 64 + 32 + c];
            const float m0 = acc0[r] * Br + w0 * Ar;
            const float m1 = acc1[r] * Br + w1 * Ar;
            if (__any(dr != prev_d)) {
                if (dr != prev_d) {
                    if (prev_d >= 0) {
                        unsafeAtomicAdd(&out[prev_d * 64 + c], r0acc);
                        unsafeAtomicAdd(&out[prev_d * 64 + 32 + c], r1acc);
                    }
                    r0acc = 0.0f;
                    r1acc = 0.0f;
                    prev_d = dr;
                }
            }
            r0acc += m0;
            r1acc += m1;
        }
        unsafeAtomicAdd(&out[prev_d * 64 + c], r0acc);
        unsafeAtomicAdd(&out[prev_d * 64 + 32 + c], r1acc);
    }

    // ---- scalar tail for E % 32 != 0 ----
    const int tail = nbatch << 5;
    if (tail < E && wid == 0) {
        for (int e = tail; e < E; ++e) {
            const int pe = perm ? perm[e] : e;
            float rf = 0.0f, pxs = 0.0f, sxs = 0.0f;
            for (int k = 0; k < 64; ++k) {
                const float f = feat[(size_t)pe * 64 + k];
                rf += f * review_w[lane * 64 + k];
                pxs += f * prob_w[k];
                sxs += f * rscore_w[k];
            }
            const float pa = __fdividef(1.0f, 1.0f + __expf(-pxs));
            const float gsv = __fdividef(1.0f, 1.0f + __expf(-sxs));
            const int s_ = src_idx[pe];
            const int d_ = dst_idx[pe];
            const float sc = cj[s_] * ci[d_];
            const float m = (weight[s_ * 64 + lane] * pa + rf * gsv) * sc;
            unsafeAtomicAdd(&out[d_ * 64 + lane], m);
        }
    }
}

extern "C" void kernel_launch(void* const* d_in, const int* in_sizes, int n_in,
                              void* d_out, int out_size, void* d_ws, size_t ws_size,
                              hipStream_t stream) {
    const float* weight    = (const float*)d_in[0];
    const float* prob_w    = (const float*)d_in[1];
    const float* rscore_w  = (const float*)d_in[2];
    const float* review_w  = (const float*)d_in[3];
    const float* feat      = (const float*)d_in[4];
    const float* cj        = (const float*)d_in[5];
    const float* ci        = (const float*)d_in[6];
    const int*   src_idx   = (const int*)d_in[7];
    const int*   dst_idx   = (const int*)d_in[8];
    float* out = (float*)d_out;
    const int E = in_sizes[7];
    const int N_DST = in_sizes[6];

    hipMemsetAsync(d_out, 0, (size_t)out_size * sizeof(float), stream);

    const size_t need = (size_t)(N_DST + E) * sizeof(int);
    int* perm = nullptr;
    if (ws_size >= need) {
        int* cursor = (int*)d_ws;
        perm = cursor + N_DST;
        hipMemsetAsync(cursor, 0, (size_t)N_DST * sizeof(int), stream);
        hist_kernel<<<1024, 256, 0, stream>>>(dst_idx, cursor, E);
        scan_kernel<<<1, 1024, 0, stream>>>(cursor, N_DST);
        scatter_kernel<<<1024, 256, 0, stream>>>(dst_idx, cursor, perm, E);
    }

    const int block = 256;
    const int grid = 2048;
    gcmc_edge_mfma<<<grid, block, 0, stream>>>(weight, prob_w, rscore_w, review_w, feat,
                                               cj, ci, src_idx, dst_idx, perm, out, E);
}